// Round 8
// baseline (57.864 us; speedup 1.0000x reference)
//
#include <hip/hip_runtime.h>

// Two-kernel YOLO decode+NMS:
//  K1 (16 blocks): decode, keys, IoU, direct firstpos rank, greedy keep, probs.
//  K2 (256 blocks): brute-force stable rank of all 1960 entries, scatter boxes/cls.
// S=7, B=2, C=20 -> 49 cells, 98 boxes, 1960 entries, 16 batch items.

constexpr int S_  = 7;
constexpr int Cc  = 20;
constexpr int NBOX  = 98;
constexpr int NENT  = 1960;
constexpr int NKPAD = 1984;    // 31 * 64
constexpr int LPRED = 1470;
constexpr int BATCH = 16;
constexpr float IOU_THR_  = 0.1f;
constexpr float PROB_THR_ = 8e-25f;

__device__ __forceinline__ unsigned long long rl64(unsigned long long v, int l)
{
    unsigned lo = (unsigned)__builtin_amdgcn_readlane((int)(unsigned)v, l);
    unsigned hi = (unsigned)__builtin_amdgcn_readlane((int)(unsigned)(v >> 32), l);
    return ((unsigned long long)hi << 32) | lo;
}

__global__ __launch_bounds__(1024)
void yolo_k1(const float* __restrict__ pred_all, float* __restrict__ out,
             unsigned* __restrict__ wsKeys, float4* __restrict__ wsBox,
             float* __restrict__ wsCls)
{
    const int b   = blockIdx.x;
    const int tid = threadIdx.x;
    const int wv  = tid >> 6, lane = tid & 63;
    const float* pred = pred_all + b * LPRED;
    float* outProbs = out + BATCH * NENT * 4 + b * NENT;

    __shared__ float s_pred[LPRED];
    __shared__ unsigned sKey[NKPAD];
    __shared__ float bXh[NBOX], bXl[NBOX], bYh[NBOX], bYl[NBOX], bA[NBOX];
    __shared__ float bPmax[NBOX];
    __shared__ unsigned bKmax[NBOX];
    __shared__ int bEmax[NBOX];
    __shared__ unsigned long long iouRow[NBOX * 2];
    __shared__ int firstpos[NBOX], boxorder[NBOX];
    __shared__ int s_nvalid;

    // ---- stage input, zero probs region (coalesced), init ----
    for (int i = tid; i < LPRED; i += 1024) s_pred[i] = pred[i];
    if (tid < NENT / 4)
        reinterpret_cast<float4*>(outProbs)[tid] = make_float4(0.f, 0.f, 0.f, 0.f);
    if (tid == 0) s_nvalid = 0;
    __syncthreads();

    // ---- decode 98 boxes (reference float32 op order); box/cls -> ws ----
    if (tid < NBOX) {
        const int bo = tid, cell = bo >> 1;
        const int ci = cell / S_, cj = cell % S_;
        const float bx = s_pred[1078 + bo * 4 + 0];
        const float by = s_pred[1078 + bo * 4 + 1];
        const float bw = s_pred[1078 + bo * 4 + 2];
        const float bh = s_pred[1078 + bo * 4 + 3];
        const float x = (bx + (float)ci) / 7.0f * 448.0f;
        const float y = (by + (float)cj) / 7.0f * 448.0f;
        const float w = bw * bw * 448.0f;
        const float h = bh * bh * 448.0f;
        wsBox[b * NBOX + bo] = make_float4(x, y, w, h);
        bXh[bo] = x + 0.5f * w;  bXl[bo] = x - 0.5f * w;
        bYh[bo] = y + 0.5f * h;  bYl[bo] = y - 0.5f * h;
        bA[bo]  = w * h;
        const float conf = s_pred[980 + bo];
        float pm = 0.f; int em = 0; unsigned msk = 0u;
        #pragma unroll
        for (int c = 0; c < Cc; ++c) {
            const float ep = s_pred[cell * Cc + c] * conf;
            if (ep > pm) { pm = ep; em = c; }   // strict > : first max (lowest c)
            if (ep >= PROB_THR_) msk |= 1u << c;
        }
        bPmax[bo] = pm;
        bKmax[bo] = (pm >= PROB_THR_) ? __float_as_uint(pm) : 0u;
        bEmax[bo] = bo * Cc + em;
        wsCls[b * NBOX + bo] = (float)(msk ? (__ffs(msk) - 1) : 0);
    }

    // ---- keys -> LDS (padded) and ws (u64 packed stores) ----
    {
        const int e0 = 2 * tid, e1 = e0 + 1;
        unsigned k0v = 0u, k1v = 0u;
        if (e1 < NENT) {
            const int bo0 = e0 / Cc, c0 = e0 - bo0 * Cc;
            const int bo1 = e1 / Cc, c1 = e1 - bo1 * Cc;
            const float ep0 = s_pred[(bo0 >> 1) * Cc + c0] * s_pred[980 + bo0];
            const float ep1 = s_pred[(bo1 >> 1) * Cc + c1] * s_pred[980 + bo1];
            if (ep0 >= PROB_THR_) k0v = __float_as_uint(ep0);
            if (ep1 >= PROB_THR_) k1v = __float_as_uint(ep1);
            *reinterpret_cast<unsigned long long*>(&wsKeys[b * NENT + e0]) =
                ((unsigned long long)k1v << 32) | k0v;
        }
        if (e0 < NKPAD) sKey[e0] = k0v;
        if (e1 < NKPAD) sKey[e1] = k1v;
    }
    __syncthreads();

    // ---- per-wave: IoU rows (ballot) + direct firstpos rank ----
    for (int r = wv; r < NBOX; r += 16) {
        const float rXh = bXh[r], rXl = bXl[r], rYh = bYh[r], rYl = bYl[r], rA = bA[r];
        bool s1 = false, s2 = false;
        {
            const int j = lane;
            const float tb = fminf(rXh, bXh[j]) - fmaxf(rXl, bXl[j]);
            const float lr = fminf(rYh, bYh[j]) - fmaxf(rYl, bYl[j]);
            const float inter = (tb < 0.0f || lr < 0.0f) ? 0.0f : tb * lr;
            const float iou = inter / (rA + bA[j] - inter);   // 0/0 -> NaN -> false
            s1 = (iou > IOU_THR_);
        }
        if (lane + 64 < NBOX) {
            const int j = lane + 64;
            const float tb = fminf(rXh, bXh[j]) - fmaxf(rXl, bXl[j]);
            const float lr = fminf(rYh, bYh[j]) - fmaxf(rYl, bYl[j]);
            const float inter = (tb < 0.0f || lr < 0.0f) ? 0.0f : tb * lr;
            const float iou = inter / (rA + bA[j] - inter);
            s2 = (iou > IOU_THR_);
        }
        const unsigned long long m1 = __ballot(s1);
        const unsigned long long m2 = __ballot(s2);
        if (lane == 0) { iouRow[r * 2] = m1; iouRow[r * 2 + 1] = m2; }
    }
    for (int bo = wv; bo < NBOX; bo += 16) {          // wave-uniform bo
        const unsigned km = bKmax[bo];                 // broadcast LDS read
        if (km == 0u) {
            if (lane == 0) firstpos[bo] = 0x7FFFFFFF;
        } else {
            const int em = bEmax[bo];
            int cnt = 0;
            #pragma unroll
            for (int it = 0; it < 31; ++it) {
                const int j = lane + 64 * it;          // pads are key 0: harmless
                const unsigned kj = sKey[j];
                cnt += __popcll(__ballot(kj > km));
                cnt += __popcll(__ballot(kj == km && j < em));
            }
            if (lane == 0) firstpos[bo] = cnt;         // ballot: same in all lanes
        }
    }
    __syncthreads();

    // ---- rank boxes by firstpos (distinct -> permutation) ----
    if (tid < NBOX) {
        const int fp = firstpos[tid];
        if (fp != 0x7FFFFFFF) {
            int r = 0;
            for (int b2 = 0; b2 < NBOX; ++b2) r += (firstpos[b2] < fp) ? 1 : 0;
            boxorder[r] = tid;
            atomicAdd(&s_nvalid, 1);
        }
    }
    __syncthreads();

    // ---- greedy keep (wave 0, readlane broadcast) + sparse prob writes ----
    if (tid < 64) {
        const int nv = s_nvalid;
        int bb0 = -1, bb1 = -1;
        unsigned long long r00 = 0, r01 = 0, r10 = 0, r11 = 0;
        if (tid < nv) {
            bb0 = boxorder[tid];
            r00 = iouRow[bb0 * 2]; r01 = iouRow[bb0 * 2 + 1];
        }
        if (tid + 64 < nv) {
            bb1 = boxorder[tid + 64];
            r10 = iouRow[bb1 * 2]; r11 = iouRow[bb1 * 2 + 1];
        }
        unsigned long long sup0 = 0, sup1 = 0, k0 = 0, k1 = 0;
        for (int r = 0; r < nv; ++r) {
            int bb; unsigned long long rw0, rw1;
            if (r < 64) {
                bb  = __builtin_amdgcn_readlane(bb0, r);
                rw0 = rl64(r00, r); rw1 = rl64(r01, r);
            } else {
                bb  = __builtin_amdgcn_readlane(bb1, r - 64);
                rw0 = rl64(r10, r - 64); rw1 = rl64(r11, r - 64);
            }
            const bool supped = (bb < 64) ? ((sup0 >> bb) & 1ull)
                                          : ((sup1 >> (bb - 64)) & 1ull);
            if (!supped) {
                if (bb < 64) k0 |= 1ull << bb; else k1 |= 1ull << (bb - 64);
                sup0 |= rw0; sup1 |= rw1;
            }
        }
        if ((k0 >> tid) & 1ull) outProbs[firstpos[tid]] = bPmax[tid];
        if (tid + 64 < NBOX && ((k1 >> tid) & 1ull))
            outProbs[firstpos[tid + 64]] = bPmax[tid + 64];
    }
}

__global__ __launch_bounds__(1024)
void yolo_k2(const unsigned* __restrict__ wsKeys, const float4* __restrict__ wsBox,
             const float* __restrict__ wsCls, float* __restrict__ out)
{
    const int it    = blockIdx.x >> 4;     // item
    const int chunk = blockIdx.x & 15;     // 16 chunks of <=123 entries
    const int tid   = threadIdx.x;
    const int wv    = tid >> 6, lane = tid & 63;

    __shared__ unsigned sKey[NKPAD];
    __shared__ float4 sBox[NBOX];
    __shared__ float  sCls[NBOX];

    for (int i = tid; i < NKPAD; i += 1024)
        sKey[i] = (i < NENT) ? wsKeys[it * NENT + i] : 0u;
    if (tid < NBOX) { sBox[tid] = wsBox[it * NBOX + tid]; sCls[tid] = wsCls[it * NBOX + tid]; }
    __syncthreads();

    // preload this lane's comparison keys into VGPRs (reused for every entry)
    unsigned kj[31];
    #pragma unroll
    for (int r = 0; r < 31; ++r) kj[r] = sKey[lane + 64 * r];

    float* outBoxes = out + it * (NENT * 4);
    float* outCls   = out + BATCH * NENT * 5 + it * NENT;

    const int base = chunk * 123;
    const int end  = min(NENT, base + 123);
    for (int e = base + wv; e < end; e += 16) {        // wave-uniform e
        const unsigned ke = sKey[e];                   // broadcast read
        int cnt = 0;
        #pragma unroll
        for (int r = 0; r < 31; ++r) {
            const int j = lane + 64 * r;               // pads: key 0, j>=1960>e
            cnt += __popcll(__ballot(kj[r] > ke));
            cnt += __popcll(__ballot(kj[r] == ke && j < e));
        }
        if (lane == 0) {                               // cnt identical in all lanes
            const int bo = e / Cc;
            *reinterpret_cast<float4*>(outBoxes + cnt * 4) = sBox[bo];
            outCls[cnt] = sCls[bo];
        }
    }
}

extern "C" void kernel_launch(void* const* d_in, const int* in_sizes, int n_in,
                              void* d_out, int out_size, void* d_ws, size_t ws_size,
                              hipStream_t stream)
{
    const float* pred = (const float*)d_in[0];
    float* out = (float*)d_out;
    unsigned* wsKeys = (unsigned*)d_ws;
    float4*   wsBox  = (float4*)((char*)d_ws + (size_t)BATCH * NENT * 4);
    float*    wsCls  = (float*)((char*)d_ws + (size_t)BATCH * NENT * 4
                                            + (size_t)BATCH * NBOX * 16);
    yolo_k1<<<BATCH, 1024, 0, stream>>>(pred, out, wsKeys, wsBox, wsCls);
    yolo_k2<<<BATCH * 16, 1024, 0, stream>>>(wsKeys, wsBox, wsCls, out);
}

// Round 9
// 32.285 us; speedup vs baseline: 1.7923x; 1.7923x over previous
//
#include <hip/hip_runtime.h>

// Single-dispatch fused YOLO decode+NMS, 272 independent blocks:
//   blocks 0..15    : per-item probs path (decode, keys, IoU, firstpos rank,
//                     serial greedy keep, sparse prob writes).
//   blocks 16..271  : 16 scatter blocks per item; each recomputes keys+boxes
//                     from the raw input and stable-ranks + scatters ~123
//                     box/cls entries (brute-force ballot rank).
// S=7, B=2, C=20 -> 49 cells, 98 boxes, 1960 entries, 16 batch items.

constexpr int S_  = 7;
constexpr int Cc  = 20;
constexpr int NBOX  = 98;
constexpr int NENT  = 1960;
constexpr int NKPAD = 1984;    // 31 * 64
constexpr int LPRED = 1470;
constexpr int BATCH = 16;
constexpr int CHUNK = 123;     // 16 * 123 = 1968 >= 1960
constexpr float IOU_THR_  = 0.1f;
constexpr float PROB_THR_ = 8e-25f;

__device__ __forceinline__ unsigned long long rl64(unsigned long long v, int l)
{
    unsigned lo = (unsigned)__builtin_amdgcn_readlane((int)(unsigned)v, l);
    unsigned hi = (unsigned)__builtin_amdgcn_readlane((int)(unsigned)(v >> 32), l);
    return ((unsigned long long)hi << 32) | lo;
}

__global__ __launch_bounds__(1024)
void yolo_fused(const float* __restrict__ pred_all, float* __restrict__ out)
{
    const int blk = blockIdx.x;
    const int tid = threadIdx.x;
    const int wv  = tid >> 6, lane = tid & 63;

    __shared__ float s_pred[LPRED];
    __shared__ unsigned sKey[NKPAD];
    // probs-path only:
    __shared__ float bXh[NBOX], bXl[NBOX], bYh[NBOX], bYl[NBOX], bA[NBOX];
    __shared__ float bPmax[NBOX];
    __shared__ unsigned bKmax[NBOX];
    __shared__ int bEmax[NBOX];
    __shared__ unsigned long long iouRow[NBOX * 2];
    __shared__ int firstpos[NBOX], boxorder[NBOX], s_nvalid;
    // scatter-path only:
    __shared__ float4 sBox[NBOX];
    __shared__ float  sCls[NBOX];

    if (blk < BATCH) {
        // ================= probs path: one block per item =================
        const int b = blk;
        const float* pred = pred_all + b * LPRED;
        float* outProbs = out + BATCH * NENT * 4 + b * NENT;

        for (int i = tid; i < LPRED; i += 1024) s_pred[i] = pred[i];
        if (tid < NENT / 4)
            reinterpret_cast<float4*>(outProbs)[tid] = make_float4(0.f,0.f,0.f,0.f);
        if (tid == 0) s_nvalid = 0;
        __syncthreads();

        // decode 98 boxes (reference float32 op order) + per-box max e-prob
        if (tid < NBOX) {
            const int bo = tid, cell = bo >> 1;
            const int ci = cell / S_, cj = cell % S_;
            const float bx = s_pred[1078 + bo * 4 + 0];
            const float by = s_pred[1078 + bo * 4 + 1];
            const float bw = s_pred[1078 + bo * 4 + 2];
            const float bh = s_pred[1078 + bo * 4 + 3];
            const float x = (bx + (float)ci) / 7.0f * 448.0f;
            const float y = (by + (float)cj) / 7.0f * 448.0f;
            const float w = bw * bw * 448.0f;
            const float h = bh * bh * 448.0f;
            bXh[bo] = x + 0.5f * w;  bXl[bo] = x - 0.5f * w;
            bYh[bo] = y + 0.5f * h;  bYl[bo] = y - 0.5f * h;
            bA[bo]  = w * h;
            const float conf = s_pred[980 + bo];
            float pm = 0.f; int em = 0;
            #pragma unroll
            for (int c = 0; c < Cc; ++c) {
                const float ep = s_pred[cell * Cc + c] * conf;
                if (ep > pm) { pm = ep; em = c; }  // first max (lowest c)
            }
            bPmax[bo] = pm;
            bKmax[bo] = (pm >= PROB_THR_) ? __float_as_uint(pm) : 0u;
            bEmax[bo] = bo * Cc + em;
        }
        // keys -> LDS
        for (int i = tid; i < NKPAD; i += 1024) {
            unsigned kv = 0u;
            if (i < NENT) {
                const int bo = i / Cc, c = i - bo * Cc;
                const float ep = s_pred[(bo >> 1) * Cc + c] * s_pred[980 + bo];
                if (ep >= PROB_THR_) kv = __float_as_uint(ep);
            }
            sKey[i] = kv;
        }
        __syncthreads();

        // IoU rows via ballot
        for (int r = wv; r < NBOX; r += 16) {
            const float rXh = bXh[r], rXl = bXl[r], rYh = bYh[r], rYl = bYl[r], rA = bA[r];
            bool s1 = false, s2 = false;
            {
                const int j = lane;
                const float tb = fminf(rXh, bXh[j]) - fmaxf(rXl, bXl[j]);
                const float lr = fminf(rYh, bYh[j]) - fmaxf(rYl, bYl[j]);
                const float inter = (tb < 0.0f || lr < 0.0f) ? 0.0f : tb * lr;
                const float iou = inter / (rA + bA[j] - inter); // 0/0->NaN->false
                s1 = (iou > IOU_THR_);
            }
            if (lane + 64 < NBOX) {
                const int j = lane + 64;
                const float tb = fminf(rXh, bXh[j]) - fmaxf(rXl, bXl[j]);
                const float lr = fminf(rYh, bYh[j]) - fmaxf(rYl, bYl[j]);
                const float inter = (tb < 0.0f || lr < 0.0f) ? 0.0f : tb * lr;
                const float iou = inter / (rA + bA[j] - inter);
                s2 = (iou > IOU_THR_);
            }
            const unsigned long long m1 = __ballot(s1);
            const unsigned long long m2 = __ballot(s2);
            if (lane == 0) { iouRow[r * 2] = m1; iouRow[r * 2 + 1] = m2; }
        }
        // direct firstpos rank: one ballot per 64 keys
        {
            unsigned kj[31];
            #pragma unroll
            for (int r = 0; r < 31; ++r) kj[r] = sKey[lane + 64 * r];
            for (int bo = wv; bo < NBOX; bo += 16) {       // wave-uniform bo
                const unsigned km = bKmax[bo];
                if (km == 0u) { if (lane == 0) firstpos[bo] = 0x7FFFFFFF; continue; }
                const int em = bEmax[bo];
                int cnt = 0;
                #pragma unroll
                for (int r = 0; r < 31; ++r) {
                    const int j = lane + 64 * r;
                    const bool c = (kj[r] > km) | ((kj[r] == km) & (j < em));
                    cnt += __popcll(__ballot(c));
                }
                if (lane == 0) firstpos[bo] = cnt;
            }
        }
        __syncthreads();

        // rank boxes by firstpos
        if (tid < NBOX) {
            const int fp = firstpos[tid];
            if (fp != 0x7FFFFFFF) {
                int r = 0;
                for (int b2 = 0; b2 < NBOX; ++b2) r += (firstpos[b2] < fp) ? 1 : 0;
                boxorder[r] = tid;
                atomicAdd(&s_nvalid, 1);
            }
        }
        __syncthreads();

        // greedy keep (wave 0) + sparse prob writes
        if (tid < 64) {
            const int nv = s_nvalid;
            int bb0 = -1, bb1 = -1;
            unsigned long long r00 = 0, r01 = 0, r10 = 0, r11 = 0;
            if (tid < nv) {
                bb0 = boxorder[tid];
                r00 = iouRow[bb0 * 2]; r01 = iouRow[bb0 * 2 + 1];
            }
            if (tid + 64 < nv) {
                bb1 = boxorder[tid + 64];
                r10 = iouRow[bb1 * 2]; r11 = iouRow[bb1 * 2 + 1];
            }
            unsigned long long sup0 = 0, sup1 = 0, k0 = 0, k1 = 0;
            for (int r = 0; r < nv; ++r) {
                int bb; unsigned long long rw0, rw1;
                if (r < 64) {
                    bb  = __builtin_amdgcn_readlane(bb0, r);
                    rw0 = rl64(r00, r); rw1 = rl64(r01, r);
                } else {
                    bb  = __builtin_amdgcn_readlane(bb1, r - 64);
                    rw0 = rl64(r10, r - 64); rw1 = rl64(r11, r - 64);
                }
                const bool supped = (bb < 64) ? ((sup0 >> bb) & 1ull)
                                              : ((sup1 >> (bb - 64)) & 1ull);
                if (!supped) {
                    if (bb < 64) k0 |= 1ull << bb; else k1 |= 1ull << (bb - 64);
                    sup0 |= rw0; sup1 |= rw1;
                }
            }
            if ((k0 >> tid) & 1ull) outProbs[firstpos[tid]] = bPmax[tid];
            if (tid + 64 < NBOX && ((k1 >> tid) & 1ull))
                outProbs[firstpos[tid + 64]] = bPmax[tid + 64];
        }
    } else {
        // ============ scatter path: 16 blocks per item, no handoff ============
        const int t = blk - BATCH;
        const int item = t >> 4, chunk = t & 15;
        const float* pred = pred_all + item * LPRED;
        float* outBoxes = out + item * (NENT * 4);
        float* outCls   = out + BATCH * NENT * 5 + item * NENT;

        for (int i = tid; i < LPRED; i += 1024) s_pred[i] = pred[i];
        __syncthreads();

        // decode boxes + cls (first class over threshold)
        if (tid < NBOX) {
            const int bo = tid, cell = bo >> 1;
            const int ci = cell / S_, cj = cell % S_;
            const float bx = s_pred[1078 + bo * 4 + 0];
            const float by = s_pred[1078 + bo * 4 + 1];
            const float bw = s_pred[1078 + bo * 4 + 2];
            const float bh = s_pred[1078 + bo * 4 + 3];
            const float x = (bx + (float)ci) / 7.0f * 448.0f;
            const float y = (by + (float)cj) / 7.0f * 448.0f;
            const float w = bw * bw * 448.0f;
            const float h = bh * bh * 448.0f;
            sBox[bo] = make_float4(x, y, w, h);
            const float conf = s_pred[980 + bo];
            unsigned msk = 0u;
            #pragma unroll
            for (int c = 0; c < Cc; ++c)
                if (s_pred[cell * Cc + c] * conf >= PROB_THR_) msk |= 1u << c;
            sCls[bo] = (float)(msk ? (__ffs(msk) - 1) : 0);
        }
        // keys -> LDS
        for (int i = tid; i < NKPAD; i += 1024) {
            unsigned kv = 0u;
            if (i < NENT) {
                const int bo = i / Cc, c = i - bo * Cc;
                const float ep = s_pred[(bo >> 1) * Cc + c] * s_pred[980 + bo];
                if (ep >= PROB_THR_) kv = __float_as_uint(ep);
            }
            sKey[i] = kv;
        }
        __syncthreads();

        // per-lane key cache, then stable rank + scatter for this chunk
        unsigned kj[31];
        #pragma unroll
        for (int r = 0; r < 31; ++r) kj[r] = sKey[lane + 64 * r];

        const int base = chunk * CHUNK;
        const int end  = min(NENT, base + CHUNK);
        for (int e = base + wv; e < end; e += 16) {       // wave-uniform e
            const unsigned ke = sKey[e];                  // broadcast read
            int cnt = 0;
            #pragma unroll
            for (int r = 0; r < 31; ++r) {
                const int j = lane + 64 * r;              // pads: key 0, j >= NENT
                const bool c = (kj[r] > ke) | ((kj[r] == ke) & (j < e));
                cnt += __popcll(__ballot(c));
            }
            if (lane == 0) {                              // cnt uniform across wave
                const int bo = e / Cc;
                *reinterpret_cast<float4*>(outBoxes + cnt * 4) = sBox[bo];
                outCls[cnt] = sCls[bo];
            }
        }
    }
}

extern "C" void kernel_launch(void* const* d_in, const int* in_sizes, int n_in,
                              void* d_out, int out_size, void* d_ws, size_t ws_size,
                              hipStream_t stream)
{
    const float* pred = (const float*)d_in[0];
    float* out = (float*)d_out;
    yolo_fused<<<BATCH + BATCH * 16, 1024, 0, stream>>>(pred, out);
}